// Round 4
// baseline (3105.049 us; speedup 1.0000x reference)
//
#include <hip/hip_runtime.h>
#include <math.h>

#define T_STEPS 4096
#define NB 16          // batch
#define NH 256         // hidden
#define BH (NB * NH)   // 4096 floats per time step
#define DT_STEP 0.1f

// ---------------- expm via Taylor series ----------------
__global__ __launch_bounds__(1024) void k_init_S(const float* __restrict__ A,
                                                 float* __restrict__ S) {
    int idx = blockIdx.x * 1024 + threadIdx.x;
    int i = idx >> 8, j = idx & 255;
    S[idx] = A[idx] + (i == j ? 1.0f : 0.0f);
}

__global__ __launch_bounds__(256) void k_expm_term(const float* __restrict__ Pprev,
                                                   const float* __restrict__ A,
                                                   float* __restrict__ Pnew,
                                                   float* __restrict__ S,
                                                   float invk) {
    __shared__ float prow[256];
    int i = blockIdx.x, j = threadIdx.x;
    prow[j] = Pprev[i * 256 + j];
    __syncthreads();
    float acc = 0.f;
#pragma unroll 8
    for (int m = 0; m < 256; ++m) acc = fmaf(prow[m], A[m * 256 + j], acc);
    float v = acc * invk;
    Pnew[i * 256 + j] = v;
    S[i * 256 + j] += v;
}

// ---------------- row-blocked GEMM (unchanged, works) ----------------
__global__ __launch_bounds__(256) void k_gemm_rows(const float* __restrict__ X,
                                                   const float* __restrict__ Wm,
                                                   const float* __restrict__ bias,
                                                   float* __restrict__ Out) {
    __shared__ float4 xs4[16][64];
    const int tid = threadIdx.x;
    const long r0 = (long)blockIdx.x * 16;
    float* xs = (float*)xs4;
#pragma unroll
    for (int rr = 0; rr < 16; ++rr) xs[rr * 256 + tid] = X[(r0 + rr) * 256 + tid];
    __syncthreads();

    float acc[16];
#pragma unroll
    for (int rr = 0; rr < 16; ++rr) acc[rr] = 0.f;

    const float4* wrow = (const float4*)(Wm + tid * 256);
    for (int d4 = 0; d4 < 64; ++d4) {
        float4 w = wrow[d4];
#pragma unroll
        for (int rr = 0; rr < 16; ++rr) {
            float4 xv = xs4[rr][d4];
            acc[rr] = fmaf(w.x, xv.x, acc[rr]);
            acc[rr] = fmaf(w.y, xv.y, acc[rr]);
            acc[rr] = fmaf(w.z, xv.z, acc[rr]);
            acc[rr] = fmaf(w.w, xv.w, acc[rr]);
        }
    }
    float b = bias[tid];
#pragma unroll
    for (int rr = 0; rr < 16; ++rr) Out[(r0 + rr) * 256 + tid] = acc[rr] + b;
}

// DPP butterfly add: x + x[lane ^ k] for k in {1,2,8} via quad_perm / row_ror:8
template <int CTRL>
__device__ __forceinline__ float dpp_add(float x) {
    int yi = __builtin_amdgcn_mov_dpp(__float_as_int(x), CTRL, 0xF, 0xF, true);
    return x + __int_as_float(yi);
}

// W fragment as 128 NAMED scalars (no arrays -> no scratch-demotion risk)
#define ALLJK(OP) \
  OP(0,0) OP(0,1) OP(0,2) OP(0,3) OP(0,4) OP(0,5) OP(0,6) OP(0,7) \
  OP(1,0) OP(1,1) OP(1,2) OP(1,3) OP(1,4) OP(1,5) OP(1,6) OP(1,7) \
  OP(2,0) OP(2,1) OP(2,2) OP(2,3) OP(2,4) OP(2,5) OP(2,6) OP(2,7) \
  OP(3,0) OP(3,1) OP(3,2) OP(3,3) OP(3,4) OP(3,5) OP(3,6) OP(3,7)

#define DW(j,k) float w##j##_##k##_x, w##j##_##k##_y, w##j##_##k##_z, w##j##_##k##_w;

#define LW(j,k) { float4 t_ = ((const float4*)(Wexp + (i0 + j) * 256 + (c << 5)))[k]; \
                  w##j##_##k##_x = t_.x; w##j##_##k##_y = t_.y;                        \
                  w##j##_##k##_z = t_.z; w##j##_##k##_w = t_.w; }

#define DACC(j) float acc##j##_x = 0.f, acc##j##_y = 0.f, acc##j##_z = 0.f, acc##j##_w = 0.f;

#define FK(j,k,HV) acc##j##_x = fmaf(w##j##_##k##_x, HV.x, acc##j##_x); \
                   acc##j##_y = fmaf(w##j##_##k##_y, HV.y, acc##j##_y); \
                   acc##j##_z = fmaf(w##j##_##k##_z, HV.z, acc##j##_z); \
                   acc##j##_w = fmaf(w##j##_##k##_w, HV.w, acc##j##_w);

#define KBLK(k) { float4 hv_ = *(const float4*)(rb + roff + ha##k);    \
                  FK(0,k,hv_) FK(1,k,hv_) FK(2,k,hv_) FK(3,k,hv_) }

#define DHA(k) const int ha##k = (c << 7) | ((((k) + c) & 7) << 4);

#define RED(j) float p##j = (acc##j##_x + acc##j##_y) + (acc##j##_z + acc##j##_w); \
               p##j = dpp_add<0xB1>(p##j);                                         \
               p##j = dpp_add<0x4E>(p##j);                                         \
               p##j = dpp_add<0x128>(p##j);

// lgkm-only barrier: no vmcnt(0) drain -> u-prefetch / hidden-store stay in flight
#define LBAR() asm volatile("s_waitcnt lgkmcnt(0)\n\ts_barrier" ::: "memory")

// ---------------- sequential scan: one block (CU) per batch element ----------------
// 512 threads = 8 waves. Wave w owns rows 32w..32w+31.
// Lane l: K-chunk c = bits{0,1,3} (32 floats), row-quad q = bits{2,4,5}.
// Each thread: 4 rows x 32-float chunk of W = 128 named-scalar VGPRs.
// h double-buffered in LDS, bank-rotation swizzle (conflict-free 8-way bcast).
// K-reduce = DPP xor1/xor2/xor8. One lgkm-barrier per step.
__global__ __launch_bounds__(512, 1) void k_scan4(const float* __restrict__ u,
                                                  const float* Wexp,   // no restrict: forbid remat
                                                  float* hidden,       // no restrict: forbid remat
                                                  float* __restrict__ hfin) {
    const int b = blockIdx.x;
    const int tid = threadIdx.x;
    const int w = tid >> 6;
    const int l = tid & 63;
    const int c = (l & 3) | ((l & 8) >> 1);          // chunk 0..7  (lane bits 0,1,3)
    const int q = ((l >> 2) & 1) | ((l >> 3) & 6);   // row-quad 0..7 (lane bits 2,4,5)
    const int i0 = (w << 5) | (q << 2);              // first of this thread's 4 rows
    const bool wr = ((l & 8) == 0);                  // writer lanes (c < 4)
    const int cc = c & 3;                            // component owned by writer lane

    __shared__ float4 hbuf[2][64];                   // h[256] double-buffered, swizzled

    ALLJK(DW)
    ALLJK(LW)

    DHA(0) DHA(1) DHA(2) DHA(3) DHA(4) DHA(5) DHA(6) DHA(7)
    const int waddr = (w << 7) | (((q + w) & 7) << 4) | (cc << 2);

    ((float*)hbuf)[tid] = 0.0f;                      // zero both buffers (512 floats)

    const float* up = u + b * NH + i0 + cc;
    float* hp = hidden + b * NH + i0 + cc;

    float u_cur = 0.f, u_nxt = 0.f, hval = 0.f;
    if (wr) {
        u_cur = up[0];
        u_nxt = up[BH];
    }
    LBAR();

    const char* rb = (const char*)hbuf;
    char* wb = (char*)hbuf;
    int roff = 0;

    for (int t = 0; t < T_STEPS; ++t) {
        float u_n2 = 0.f;
        if (wr && t + 2 < T_STEPS) u_n2 = up[(size_t)(t + 2) * BH];

        DACC(0) DACC(1) DACC(2) DACC(3)
        KBLK(0) KBLK(1)
        __builtin_amdgcn_sched_barrier(0);
        KBLK(2) KBLK(3)
        __builtin_amdgcn_sched_barrier(0);
        KBLK(4) KBLK(5)
        __builtin_amdgcn_sched_barrier(0);
        KBLK(6) KBLK(7)

        RED(0) RED(1) RED(2) RED(3)
        float y = (c & 2) ? ((c & 1) ? p3 : p2) : ((c & 1) ? p1 : p0);

        if (wr) {
            float xa = u_cur - y;
            xa = fminf(fmaxf(xa, -9.0f), 9.0f);
            float E = __expf(2.0f * xa);
            float th = (E - 1.0f) * __builtin_amdgcn_rcpf(E + 1.0f);
            hval = fmaf(DT_STEP, th, hval);
            *(float*)(wb + (roff ^ 1024) + waddr) = hval;   // next h buffer
            hp[(size_t)t * BH] = hval;                      // stage for output GEMM
        }
        u_cur = u_nxt;
        u_nxt = u_n2;
        roff ^= 1024;
        LBAR();
    }
    if (wr) hfin[b * NH + i0 + cc] = hval;
}

extern "C" void kernel_launch(void* const* d_in, const int* in_sizes, int n_in,
                              void* d_out, int out_size, void* d_ws, size_t ws_size,
                              hipStream_t stream) {
    const float* x     = (const float*)d_in[0];  // [T,B,D]
    const float* U_w   = (const float*)d_in[1];  // [H,D]
    const float* U_b   = (const float*)d_in[2];  // [H]
    const float* W_log = (const float*)d_in[3];  // [H,H]
    const float* c_w   = (const float*)d_in[4];  // [O,H]
    const float* c_b   = (const float*)d_in[5];  // [O]

    float* out    = (float*)d_out;
    float* hidden = out;                          // stage hidden in d_out, then in-place GEMM
    float* hfin   = out + (long)T_STEPS * BH;     // second output chunk

    float* ws = (float*)d_ws;
    float* S  = ws;                // 65536 floats: Wexp accumulator
    float* Pa = ws + 65536;
    float* Pb = ws + 2 * 65536;
    float* u  = ws + 3 * 65536;    // 16,777,216 floats

    // Wexp = expm(W_log), Taylor K=9 (||W_log||_2 ~ 0.32 -> remainder ~1e-9)
    k_init_S<<<64, 1024, 0, stream>>>(W_log, S);
    const float* prev = W_log;
    float* cur = Pa;
    for (int k = 2; k <= 9; ++k) {
        k_expm_term<<<256, 256, 0, stream>>>(prev, W_log, cur, S, 1.0f / (float)k);
        prev = cur;
        cur = (cur == Pa) ? Pb : Pa;
    }

    // u = x @ U_w^T + U_b
    k_gemm_rows<<<4096, 256, 0, stream>>>(x, U_w, U_b, u);

    // sequential recurrence, hidden -> d_out
    k_scan4<<<NB, 512, 0, stream>>>(u, S, hidden, hfin);

    // out = hidden @ c_w^T + c_b, in place
    k_gemm_rows<<<4096, 256, 0, stream>>>(hidden, c_w, c_b, hidden);
}